// Round 3
// baseline (1992.114 us; speedup 1.0000x reference)
//
#include <hip/hip_runtime.h>

#define TLEN 4096
#define DIM 1024
#define NHEAD 16
#define HDIM 64
#define QKV_COLS (3 * DIM)

// Softmax normalization state in module-scope device globals (not d_ws).
__device__ float g_Lsum[NHEAD];
__device__ float g_recipL[NHEAD];

__global__ void zeroL() {
    if (threadIdx.x < NHEAD) g_Lsum[threadIdx.x] = 0.0f;
}

__global__ void recipL() {
    if (threadIdx.x < NHEAD) g_recipL[threadIdx.x] = 1.0f / g_Lsum[threadIdx.x];
}

// C[m,n] = sum_k A[m,k]*scale(k) * B[n,k]   (A: MxK row-major, B: NxK row-major)
// USE_SCALE: multiply A[:,k] by g_recipL[k/64] (folds softmax 1/L into out-proj).
template <bool USE_SCALE>
__global__ __launch_bounds__(256) void gemm_abt(
    const float* __restrict__ A, const float* __restrict__ B,
    float* __restrict__ C, int M, int N, int K)
{
    __shared__ float As[16][68];   // [k][m], padded
    __shared__ float Bs[16][68];   // [k][n], padded
    const int tid = threadIdx.x;
    const int tx = tid & 15, ty = tid >> 4;
    const int m0 = blockIdx.x * 64, n0 = blockIdx.y * 64;
    const int lr = tid >> 2;          // 0..63
    const int lc = (tid & 3) << 2;    // 0,4,8,12

    float acc[4][4] = {};
    for (int k0 = 0; k0 < K; k0 += 16) {
        // 64 rows x 16 k-cols per tile = 1024 elems = 256 threads x 4  (exact)
        float s = USE_SCALE ? g_recipL[k0 >> 6] : 1.0f;
        float4 a = *(const float4*)(A + (size_t)(m0 + lr) * K + k0 + lc);
        float4 b = *(const float4*)(B + (size_t)(n0 + lr) * K + k0 + lc);
        As[lc + 0][lr] = a.x * s; As[lc + 1][lr] = a.y * s;
        As[lc + 2][lr] = a.z * s; As[lc + 3][lr] = a.w * s;
        Bs[lc + 0][lr] = b.x; Bs[lc + 1][lr] = b.y;
        Bs[lc + 2][lr] = b.z; Bs[lc + 3][lr] = b.w;
        __syncthreads();
#pragma unroll
        for (int kk = 0; kk < 16; ++kk) {
            float4 av = *(const float4*)&As[kk][ty * 4];
            float4 bv = *(const float4*)&Bs[kk][tx * 4];
            float aa[4] = {av.x, av.y, av.z, av.w};
            float bb[4] = {bv.x, bv.y, bv.z, bv.w};
#pragma unroll
            for (int i = 0; i < 4; ++i)
#pragma unroll
                for (int j = 0; j < 4; ++j)
                    acc[i][j] += aa[i] * bb[j];
        }
        __syncthreads();
    }
#pragma unroll
    for (int i = 0; i < 4; ++i) {
        float4 o = make_float4(acc[i][0], acc[i][1], acc[i][2], acc[i][3]);
        *(float4*)(C + (size_t)(m0 + ty * 4 + i) * N + n0 + tx * 4) = o;
    }
}

// One block per (64-row Q tile, head). Computes unnormalized
// attn'[t, h*64+d] = sum_s exp(0.125 * q_t . k_s) * v_s[d]
// and accumulates per-head L[h] = sum exp(...) via one atomicAdd per block.
// (Joint softmax over the whole TxT per head is linear in 1/L -> fold later.
//  No max subtraction needed: scaled scores ~ N(0,1), exp can't overflow fp32.)
__global__ __launch_bounds__(256) void attn_fused(
    const float* __restrict__ qkv, float* __restrict__ attnbuf)
{
    __shared__ float Qs[64][68];  // [d][t]
    __shared__ float Ks[64][68];  // [d][s]
    __shared__ float Vs[64][68];  // [s][d]
    __shared__ float Ps[64][68];  // [s][t]
    __shared__ float red[256];

    const int tid = threadIdx.x;
    const int tx = tid & 15, ty = tid >> 4;
    const int t0 = blockIdx.x * 64;
    const int h  = blockIdx.y;
    const int lr = tid >> 2;        // 0..63
    const int lc = (tid & 3) << 2;  // 0,4,8,12

    // Stage full 64x64 Q tile transposed (Qs[d][t]):
    // 4 chunk-iterations x 256 threads x 4 floats = 4096 = full tile.
#pragma unroll
    for (int c0 = 0; c0 < HDIM; c0 += 16) {
        float4 q = *(const float4*)(qkv + (size_t)(t0 + lr) * QKV_COLS + h * HDIM + c0 + lc);
        Qs[c0 + lc + 0][lr] = q.x; Qs[c0 + lc + 1][lr] = q.y;
        Qs[c0 + lc + 2][lr] = q.z; Qs[c0 + lc + 3][lr] = q.w;
    }

    float oacc[4][4] = {};
    float lsum = 0.0f;

    for (int s0 = 0; s0 < TLEN; s0 += 64) {
        __syncthreads();  // prev iter's Ps/Vs readers done; Qs staged (iter 0)
#pragma unroll
        for (int c0 = 0; c0 < HDIM; c0 += 16) {
            float4 k = *(const float4*)(qkv + (size_t)(s0 + lr) * QKV_COLS + DIM + h * HDIM + c0 + lc);
            Ks[c0 + lc + 0][lr] = k.x; Ks[c0 + lc + 1][lr] = k.y;
            Ks[c0 + lc + 2][lr] = k.z; Ks[c0 + lc + 3][lr] = k.w;
            float4 v = *(const float4*)(qkv + (size_t)(s0 + lr) * QKV_COLS + 2 * DIM + h * HDIM + c0 + lc);
            *(float4*)&Vs[lr][c0 + lc] = v;
        }
        __syncthreads();

        // scores: S[t][s] = sum_d Q[t][d]*K[s][d]
        float sacc[4][4] = {};
#pragma unroll
        for (int d = 0; d < HDIM; ++d) {
            float4 qv = *(const float4*)&Qs[d][ty * 4];
            float4 kv = *(const float4*)&Ks[d][tx * 4];
            float qa[4] = {qv.x, qv.y, qv.z, qv.w};
            float ka[4] = {kv.x, kv.y, kv.z, kv.w};
#pragma unroll
            for (int i = 0; i < 4; ++i)
#pragma unroll
                for (int j = 0; j < 4; ++j)
                    sacc[i][j] += qa[i] * ka[j];
        }

        // p = exp(score / sqrt(64)); store transposed Ps[s][t]
#pragma unroll
        for (int i = 0; i < 4; ++i)
#pragma unroll
            for (int j = 0; j < 4; ++j) {
                float p = __expf(sacc[i][j] * 0.125f);
                lsum += p;
                Ps[tx * 4 + j][ty * 4 + i] = p;
            }
        __syncthreads();

        // O[t][d] += sum_s P[t][s]*V[s][d]
#pragma unroll
        for (int s = 0; s < 64; ++s) {
            float4 pv = *(const float4*)&Ps[s][ty * 4];
            float4 vv = *(const float4*)&Vs[s][tx * 4];
            float pa[4] = {pv.x, pv.y, pv.z, pv.w};
            float va[4] = {vv.x, vv.y, vv.z, vv.w};
#pragma unroll
            for (int i = 0; i < 4; ++i)
#pragma unroll
                for (int j = 0; j < 4; ++j)
                    oacc[i][j] += pa[i] * va[j];
        }
    }

    // Write unnormalized attn' (normalization folded into out-proj)
#pragma unroll
    for (int i = 0; i < 4; ++i) {
        float4 o = make_float4(oacc[i][0], oacc[i][1], oacc[i][2], oacc[i][3]);
        *(float4*)(attnbuf + (size_t)(t0 + ty * 4 + i) * DIM + h * HDIM + tx * 4) = o;
    }

    // Block-reduce lsum in LDS, one atomic per block
    red[tid] = lsum;
    __syncthreads();
    for (int off = 128; off > 0; off >>= 1) {
        if (tid < off) red[tid] += red[tid + off];
        __syncthreads();
    }
    if (tid == 0) atomicAdd(&g_Lsum[h], red[0]);
}

extern "C" void kernel_launch(void* const* d_in, const int* in_sizes, int n_in,
                              void* d_out, int out_size, void* d_ws, size_t ws_size,
                              hipStream_t stream)
{
    const float* x     = (const float*)d_in[0];   // [4096, 1024]
    const float* W_in  = (const float*)d_in[1];   // [3072, 1024]
    const float* W_out = (const float*)d_in[2];   // [1024, 1024]
    float* out = (float*)d_out;                   // [4096, 1024]

    char* ws = (char*)d_ws;
    float* qkv   = (float*)ws;                                  // 50,331,648 B
    float* attnb = (float*)(ws + (size_t)TLEN * QKV_COLS * 4);  // 16,777,216 B
    // total ws use: exactly 64 MiB.

    zeroL<<<1, 64, 0, stream>>>();

    // qkv = x @ W_in^T
    gemm_abt<false><<<dim3(TLEN / 64, QKV_COLS / 64), 256, 0, stream>>>(
        x, W_in, qkv, TLEN, QKV_COLS, DIM);

    // unnormalized attention + per-head sum of exp
    attn_fused<<<dim3(TLEN / 64, NHEAD), 256, 0, stream>>>(qkv, attnb);

    recipL<<<1, 64, 0, stream>>>();

    // out = (attn'/L) @ W_out^T  (1/L folded into A staging)
    gemm_abt<true><<<dim3(TLEN / 64, DIM / 64), 256, 0, stream>>>(
        attnb, W_out, out, TLEN, DIM, DIM);
}

// Round 4
// 804.785 us; speedup vs baseline: 2.4753x; 2.4753x over previous
//
#include <hip/hip_runtime.h>

#define TLEN 4096
#define DIM 1024
#define NHEAD 16
#define HDIM 64
#define QKV_COLS (3 * DIM)

typedef __attribute__((ext_vector_type(8))) short short8;   // 8 bf16 = 4 VGPR (MFMA A/B frag)
typedef __attribute__((ext_vector_type(4))) float f32x4;    // MFMA C/D frag

struct alignas(8) s4 { short v[4]; };

__device__ float g_Lsum[NHEAD];
__device__ float g_recipL[NHEAD];

__global__ void zeroL() {
    if (threadIdx.x < NHEAD) g_Lsum[threadIdx.x] = 0.0f;
}
__global__ void recipL() {
    if (threadIdx.x < NHEAD) g_recipL[threadIdx.x] = 1.0f / g_Lsum[threadIdx.x];
}

__device__ __forceinline__ unsigned bf16_rtne_bits(float x) {
    unsigned u = __float_as_uint(x);
    return (u + 0x7fffu + ((u >> 16) & 1u)) >> 16;
}

// qkv = A @ B^T, output written as split bf16 planes: hi = RTNE(x), lo = trunc(x - hi).
__global__ __launch_bounds__(256) void gemm_qkv(
    const float* __restrict__ A, const float* __restrict__ B,
    short* __restrict__ Chi, short* __restrict__ Clo, int M, int N, int K)
{
    __shared__ float As[16][68];
    __shared__ float Bs[16][68];
    const int tid = threadIdx.x;
    const int tx = tid & 15, ty = tid >> 4;
    const int m0 = blockIdx.x * 64, n0 = blockIdx.y * 64;
    const int lr = tid >> 2;
    const int lc = (tid & 3) << 2;

    float acc[4][4] = {};
    for (int k0 = 0; k0 < K; k0 += 16) {
        float4 a = *(const float4*)(A + (size_t)(m0 + lr) * K + k0 + lc);
        float4 b = *(const float4*)(B + (size_t)(n0 + lr) * K + k0 + lc);
        As[lc + 0][lr] = a.x; As[lc + 1][lr] = a.y;
        As[lc + 2][lr] = a.z; As[lc + 3][lr] = a.w;
        Bs[lc + 0][lr] = b.x; Bs[lc + 1][lr] = b.y;
        Bs[lc + 2][lr] = b.z; Bs[lc + 3][lr] = b.w;
        __syncthreads();
#pragma unroll
        for (int kk = 0; kk < 16; ++kk) {
            float4 av = *(const float4*)&As[kk][ty * 4];
            float4 bv = *(const float4*)&Bs[kk][tx * 4];
            float aa[4] = {av.x, av.y, av.z, av.w};
            float bb[4] = {bv.x, bv.y, bv.z, bv.w};
#pragma unroll
            for (int i = 0; i < 4; ++i)
#pragma unroll
                for (int j = 0; j < 4; ++j)
                    acc[i][j] += aa[i] * bb[j];
        }
        __syncthreads();
    }
#pragma unroll
    for (int i = 0; i < 4; ++i) {
        s4 hv, lv;
#pragma unroll
        for (int j = 0; j < 4; ++j) {
            float x = acc[i][j];
            unsigned hb = bf16_rtne_bits(x);
            float hf = __uint_as_float(hb << 16);
            float lo = x - hf;
            hv.v[j] = (short)hb;
            lv.v[j] = (short)(__float_as_uint(lo) >> 16);
        }
        size_t off = (size_t)(m0 + ty * 4 + i) * N + n0 + tx * 4;
        *(s4*)(Chi + off) = hv;
        *(s4*)(Clo + off) = lv;
    }
}

// One block per (64-row Q tile, head). bf16 MFMA attention:
// scores = (Qhi+Qlo).(Khi+Klo)^T via 3-term split MFMA (hi*hi + lo*hi + hi*lo),
// P = bf16(exp(s/8)) (lsum accumulates the ROUNDED P for exact consistency),
// O += P @ V via plain bf16 MFMA. Normalization 1/L folded into out-proj.
__global__ __launch_bounds__(256) void attn_mfma(
    const short* __restrict__ qkv_hi, const short* __restrict__ qkv_lo,
    float* __restrict__ attnbuf)
{
    __shared__ short Qhi[64][72], Qlo[64][72];   // [t][d]
    __shared__ short Khi[64][72], Klo[64][72];   // [s][d]
    __shared__ short Vt[64][72];                 // [d][s]  (transposed)
    __shared__ short Ps[64][72];                 // [t][s]
    __shared__ float red[256];

    const int tid = threadIdx.x;
    const int t0 = blockIdx.x * 64;
    const int h  = blockIdx.y;
    const int lr  = tid >> 2;          // 0..63: tile row for staging
    const int lc4 = (tid & 3) << 2;    // 0,4,8,12
    const int wv   = tid >> 6;         // wave 0..3
    const int lane = tid & 63;
    const int fr   = lane & 15;        // frag row/col index
    const int quad = lane >> 4;        // 0..3

    // ---- stage Q tile (hi+lo), natural [t][d] ----
#pragma unroll
    for (int c0 = 0; c0 < HDIM; c0 += 16) {
        int d = c0 + lc4;
        size_t off = (size_t)(t0 + lr) * QKV_COLS + h * HDIM + d;
        *(s4*)&Qhi[lr][d] = *(const s4*)(qkv_hi + off);
        *(s4*)&Qlo[lr][d] = *(const s4*)(qkv_lo + off);
    }
    __syncthreads();

    // ---- preload Q fragments (loop-invariant): A-frag [m=fr][k=quad*8+j] ----
    short8 qh0 = *(const short8*)&Qhi[wv * 16 + fr][quad * 8];
    short8 qh1 = *(const short8*)&Qhi[wv * 16 + fr][32 + quad * 8];
    short8 ql0 = *(const short8*)&Qlo[wv * 16 + fr][quad * 8];
    short8 ql1 = *(const short8*)&Qlo[wv * 16 + fr][32 + quad * 8];

    f32x4 oacc[4] = {};   // O[t=wv*16..+16][d-tile j], C-layout
    float lsum = 0.0f;

    for (int s0 = 0; s0 < TLEN; s0 += 64) {
        __syncthreads();  // prev-iter readers of Khi/Klo/Vt done
        // ---- stage K (hi+lo, [s][d]) and V (hi only, transposed [d][s]) ----
#pragma unroll
        for (int c0 = 0; c0 < HDIM; c0 += 16) {
            int d = c0 + lc4;
            size_t koff = (size_t)(s0 + lr) * QKV_COLS + DIM + h * HDIM + d;
            *(s4*)&Khi[lr][d] = *(const s4*)(qkv_hi + koff);
            *(s4*)&Klo[lr][d] = *(const s4*)(qkv_lo + koff);
            s4 vv = *(const s4*)(qkv_hi + (size_t)(s0 + lr) * QKV_COLS + 2 * DIM + h * HDIM + d);
            Vt[d + 0][lr] = vv.v[0];
            Vt[d + 1][lr] = vv.v[1];
            Vt[d + 2][lr] = vv.v[2];
            Vt[d + 3][lr] = vv.v[3];
        }
        __syncthreads();

        // ---- scores + exp + P write; wave wv owns t-rows [wv*16, wv*16+16) ----
#pragma unroll
        for (int j = 0; j < 4; ++j) {   // s-tile
            short8 kh0 = *(const short8*)&Khi[j * 16 + fr][quad * 8];
            short8 kh1 = *(const short8*)&Khi[j * 16 + fr][32 + quad * 8];
            short8 kl0 = *(const short8*)&Klo[j * 16 + fr][quad * 8];
            short8 kl1 = *(const short8*)&Klo[j * 16 + fr][32 + quad * 8];
            f32x4 acc = {};
            acc = __builtin_amdgcn_mfma_f32_16x16x32_bf16(qh0, kh0, acc, 0, 0, 0);
            acc = __builtin_amdgcn_mfma_f32_16x16x32_bf16(qh1, kh1, acc, 0, 0, 0);
            acc = __builtin_amdgcn_mfma_f32_16x16x32_bf16(ql0, kh0, acc, 0, 0, 0);
            acc = __builtin_amdgcn_mfma_f32_16x16x32_bf16(ql1, kh1, acc, 0, 0, 0);
            acc = __builtin_amdgcn_mfma_f32_16x16x32_bf16(qh0, kl0, acc, 0, 0, 0);
            acc = __builtin_amdgcn_mfma_f32_16x16x32_bf16(qh1, kl1, acc, 0, 0, 0);
            // C-layout: element r -> (t = wv*16 + quad*4 + r, s = j*16 + fr)
#pragma unroll
            for (int r = 0; r < 4; ++r) {
                float p = __expf(acc[r] * 0.125f);
                unsigned hb = bf16_rtne_bits(p);
                lsum += __uint_as_float(hb << 16);   // sum the ROUNDED p
                Ps[wv * 16 + quad * 4 + r][j * 16 + fr] = (short)hb;
            }
        }
        __syncthreads();  // P visible (own-wave ordering + Vt already staged)

        // ---- O += P @ V : A-frag from Ps (own rows), B-frag from Vt ----
        short8 p0 = *(const short8*)&Ps[wv * 16 + fr][quad * 8];
        short8 p1 = *(const short8*)&Ps[wv * 16 + fr][32 + quad * 8];
#pragma unroll
        for (int j = 0; j < 4; ++j) {   // d-tile
            short8 v0 = *(const short8*)&Vt[j * 16 + fr][quad * 8];
            short8 v1 = *(const short8*)&Vt[j * 16 + fr][32 + quad * 8];
            oacc[j] = __builtin_amdgcn_mfma_f32_16x16x32_bf16(p0, v0, oacc[j], 0, 0, 0);
            oacc[j] = __builtin_amdgcn_mfma_f32_16x16x32_bf16(p1, v1, oacc[j], 0, 0, 0);
        }
    }

    // ---- write unnormalized O: C-layout (t = wv*16+quad*4+r, d = j*16+fr) ----
#pragma unroll
    for (int j = 0; j < 4; ++j)
#pragma unroll
        for (int r = 0; r < 4; ++r)
            attnbuf[(size_t)(t0 + wv * 16 + quad * 4 + r) * DIM + h * HDIM + j * 16 + fr] = oacc[j][r];

    // ---- block-reduce lsum, one atomic per block ----
    red[tid] = lsum;
    __syncthreads();
    for (int off = 128; off > 0; off >>= 1) {
        if (tid < off) red[tid] += red[tid + off];
        __syncthreads();
    }
    if (tid == 0) atomicAdd(&g_Lsum[h], red[0]);
}

// out = (attn'/L) @ W_out^T, fp32 VALU; 1/L folded into A staging per 64-col head group.
__global__ __launch_bounds__(256) void gemm_out(
    const float* __restrict__ A, const float* __restrict__ B,
    float* __restrict__ C, int M, int N, int K)
{
    __shared__ float As[16][68];
    __shared__ float Bs[16][68];
    const int tid = threadIdx.x;
    const int tx = tid & 15, ty = tid >> 4;
    const int m0 = blockIdx.x * 64, n0 = blockIdx.y * 64;
    const int lr = tid >> 2;
    const int lc = (tid & 3) << 2;

    float acc[4][4] = {};
    for (int k0 = 0; k0 < K; k0 += 16) {
        float s = g_recipL[k0 >> 6];
        float4 a = *(const float4*)(A + (size_t)(m0 + lr) * K + k0 + lc);
        float4 b = *(const float4*)(B + (size_t)(n0 + lr) * K + k0 + lc);
        As[lc + 0][lr] = a.x * s; As[lc + 1][lr] = a.y * s;
        As[lc + 2][lr] = a.z * s; As[lc + 3][lr] = a.w * s;
        Bs[lc + 0][lr] = b.x; Bs[lc + 1][lr] = b.y;
        Bs[lc + 2][lr] = b.z; Bs[lc + 3][lr] = b.w;
        __syncthreads();
#pragma unroll
        for (int kk = 0; kk < 16; ++kk) {
            float4 av = *(const float4*)&As[kk][ty * 4];
            float4 bv = *(const float4*)&Bs[kk][tx * 4];
            float aa[4] = {av.x, av.y, av.z, av.w};
            float bb[4] = {bv.x, bv.y, bv.z, bv.w};
#pragma unroll
            for (int i = 0; i < 4; ++i)
#pragma unroll
                for (int j = 0; j < 4; ++j)
                    acc[i][j] += aa[i] * bb[j];
        }
        __syncthreads();
    }
#pragma unroll
    for (int i = 0; i < 4; ++i) {
        float4 o = make_float4(acc[i][0], acc[i][1], acc[i][2], acc[i][3]);
        *(float4*)(C + (size_t)(m0 + ty * 4 + i) * N + n0 + tx * 4) = o;
    }
}

extern "C" void kernel_launch(void* const* d_in, const int* in_sizes, int n_in,
                              void* d_out, int out_size, void* d_ws, size_t ws_size,
                              hipStream_t stream)
{
    const float* x     = (const float*)d_in[0];   // [4096, 1024]
    const float* W_in  = (const float*)d_in[1];   // [3072, 1024]
    const float* W_out = (const float*)d_in[2];   // [1024, 1024]
    float* out = (float*)d_out;                   // [4096, 1024]

    char* ws = (char*)d_ws;
    short* qkv_hi = (short*)ws;                                        // 25,165,824 B
    short* qkv_lo = (short*)(ws + (size_t)TLEN * QKV_COLS * 2);        // 25,165,824 B
    float* attnb  = (float*)(ws + (size_t)TLEN * QKV_COLS * 4);        // 16,777,216 B
    // total: exactly 64 MiB (same footprint as the passing round).

    zeroL<<<1, 64, 0, stream>>>();

    gemm_qkv<<<dim3(TLEN / 64, QKV_COLS / 64), 256, 0, stream>>>(
        x, W_in, qkv_hi, qkv_lo, TLEN, QKV_COLS, DIM);

    attn_mfma<<<dim3(TLEN / 64, NHEAD), 256, 0, stream>>>(qkv_hi, qkv_lo, attnb);

    recipL<<<1, 64, 0, stream>>>();

    gemm_out<<<dim3(TLEN / 64, DIM / 64), 256, 0, stream>>>(
        attnb, W_out, out, TLEN, DIM, DIM);
}

// Round 5
// 319.557 us; speedup vs baseline: 6.2340x; 2.5184x over previous
//
#include <hip/hip_runtime.h>

#define TLEN 4096
#define DIM 1024
#define NHEAD 16
#define HDIM 64
#define QKV_COLS (3 * DIM)

typedef __attribute__((ext_vector_type(8))) short short8;   // 8 bf16 = 4 VGPR (MFMA A/B frag)
typedef __attribute__((ext_vector_type(4))) float f32x4;    // MFMA C/D frag

struct alignas(8) s4 { short v[4]; };

__device__ float g_Lsum[NHEAD];
__device__ float g_recipL[NHEAD];

__global__ void zeroL() {
    if (threadIdx.x < NHEAD) g_Lsum[threadIdx.x] = 0.0f;
}
__global__ void recipL() {
    if (threadIdx.x < NHEAD) g_recipL[threadIdx.x] = 1.0f / g_Lsum[threadIdx.x];
}

__device__ __forceinline__ unsigned bf16_rtne_bits(float x) {
    unsigned u = __float_as_uint(x);
    return (u + 0x7fffu + ((u >> 16) & 1u)) >> 16;
}

// fp32 -> bf16 (RTNE), vectorized; n4 = element count / 4.
__global__ __launch_bounds__(256) void conv_bf16(
    const float* __restrict__ src, short* __restrict__ dst, int n4)
{
    int i = blockIdx.x * 256 + threadIdx.x;
    if (i < n4) {
        float4 v = ((const float4*)src)[i];
        s4 o;
        o.v[0] = (short)bf16_rtne_bits(v.x);
        o.v[1] = (short)bf16_rtne_bits(v.y);
        o.v[2] = (short)bf16_rtne_bits(v.z);
        o.v[3] = (short)bf16_rtne_bits(v.w);
        ((s4*)dst)[i] = o;
    }
}

// W_out [1024,1024] -> bf16 with per-head 1/L folded in (k-group = k/64).
__global__ __launch_bounds__(256) void conv_wout(
    const float* __restrict__ src, short* __restrict__ dst)
{
    int i = blockIdx.x * 256 + threadIdx.x;   // over 1024*1024/4
    float s = g_recipL[(i & 255) >> 4];       // k = (i&255)*4; head = k>>6
    float4 v = ((const float4*)src)[i];
    s4 o;
    o.v[0] = (short)bf16_rtne_bits(v.x * s);
    o.v[1] = (short)bf16_rtne_bits(v.y * s);
    o.v[2] = (short)bf16_rtne_bits(v.z * s);
    o.v[3] = (short)bf16_rtne_bits(v.w * s);
    ((s4*)dst)[i] = o;
}

// C = A @ B^T, bf16 MFMA. A:[M,K] bf16, B:[N,K] bf16, C: bf16 or fp32.
// 128x128 tile per block, 4 waves in 2x2, BK=32, 16 MFMA + 8 ds_read_b128
// per wave per k-iter. M,N % 128 == 0, K % 32 == 0.
template <bool OUT_BF16>
__global__ __launch_bounds__(256) void gemm_bt(
    const short* __restrict__ A, const short* __restrict__ B,
    void* __restrict__ Cout, int M, int N, int K)
{
    __shared__ short As[128][32];   // 8 KB, row = 64 B
    __shared__ short Bs[128][32];   // 8 KB
    const int tid  = threadIdx.x;
    const int wv   = tid >> 6, lane = tid & 63;
    const int fr   = lane & 15, quad = lane >> 4;
    const int wm   = (wv >> 1) * 64, wn = (wv & 1) * 64;
    const int m0 = blockIdx.x * 128, n0 = blockIdx.y * 128;

    f32x4 acc[4][4] = {};

    for (int k0 = 0; k0 < K; k0 += 32) {
        __syncthreads();   // previous iter's readers done
        // stage 128x32 A and B tiles: 512 16-B chunks each, 2 per thread
#pragma unroll
        for (int c = tid; c < 512; c += 256) {
            int row = c >> 2, col = (c & 3) * 8;
            *(uint4*)&As[row][col] = *(const uint4*)(A + (size_t)(m0 + row) * K + k0 + col);
            *(uint4*)&Bs[row][col] = *(const uint4*)(B + (size_t)(n0 + row) * K + k0 + col);
        }
        __syncthreads();

        short8 af[4], bfr[4];
#pragma unroll
        for (int i = 0; i < 4; ++i) {
            af[i]  = *(const short8*)&As[wm + i * 16 + fr][quad * 8];
            bfr[i] = *(const short8*)&Bs[wn + i * 16 + fr][quad * 8];
        }
#pragma unroll
        for (int i = 0; i < 4; ++i)
#pragma unroll
            for (int j = 0; j < 4; ++j)
                acc[i][j] = __builtin_amdgcn_mfma_f32_16x16x32_bf16(af[i], bfr[j], acc[i][j], 0, 0, 0);
    }

    // C element: m = m0+wm+i*16+quad*4+r, n = n0+wn+j*16+fr
#pragma unroll
    for (int i = 0; i < 4; ++i)
#pragma unroll
        for (int j = 0; j < 4; ++j)
#pragma unroll
            for (int r = 0; r < 4; ++r) {
                size_t off = (size_t)(m0 + wm + i * 16 + quad * 4 + r) * N + n0 + wn + j * 16 + fr;
                if (OUT_BF16)
                    ((short*)Cout)[off] = (short)bf16_rtne_bits(acc[i][j][r]);
                else
                    ((float*)Cout)[off] = acc[i][j][r];
            }
}

// One block per (64-row Q tile, head), plain bf16 MFMA attention.
// P = bf16(exp(s/8)); lsum sums the ROUNDED P; O unnormalized (1/L in out-proj).
__global__ __launch_bounds__(256) void attn_mfma(
    const short* __restrict__ qkvb, short* __restrict__ attnb)
{
    __shared__ short Qs[64][72];   // [t][d]
    __shared__ short Ks[64][72];   // [s][d]
    __shared__ short Vt[64][72];   // [d][s]  (transposed)
    __shared__ short Ps[64][72];   // [t][s]
    __shared__ float red[256];

    const int tid = threadIdx.x;
    const int t0 = blockIdx.x * 64;
    const int h  = blockIdx.y;
    const int lr  = tid >> 2;
    const int lc4 = (tid & 3) << 2;
    const int wv   = tid >> 6;
    const int lane = tid & 63;
    const int fr   = lane & 15;
    const int quad = lane >> 4;

    // stage Q tile [t][d]
#pragma unroll
    for (int c0 = 0; c0 < HDIM; c0 += 16) {
        int d = c0 + lc4;
        *(s4*)&Qs[lr][d] = *(const s4*)(qkvb + (size_t)(t0 + lr) * QKV_COLS + h * HDIM + d);
    }
    __syncthreads();

    short8 q0 = *(const short8*)&Qs[wv * 16 + fr][quad * 8];
    short8 q1 = *(const short8*)&Qs[wv * 16 + fr][32 + quad * 8];

    f32x4 oacc[4] = {};
    float lsum = 0.0f;

    for (int s0 = 0; s0 < TLEN; s0 += 64) {
        __syncthreads();
#pragma unroll
        for (int c0 = 0; c0 < HDIM; c0 += 16) {
            int d = c0 + lc4;
            *(s4*)&Ks[lr][d] = *(const s4*)(qkvb + (size_t)(s0 + lr) * QKV_COLS + DIM + h * HDIM + d);
            s4 vvv = *(const s4*)(qkvb + (size_t)(s0 + lr) * QKV_COLS + 2 * DIM + h * HDIM + d);
            Vt[d + 0][lr] = vvv.v[0];
            Vt[d + 1][lr] = vvv.v[1];
            Vt[d + 2][lr] = vvv.v[2];
            Vt[d + 3][lr] = vvv.v[3];
        }
        __syncthreads();

        // scores + exp + P; wave wv owns t-rows [wv*16, wv*16+16)
#pragma unroll
        for (int j = 0; j < 4; ++j) {
            short8 k0 = *(const short8*)&Ks[j * 16 + fr][quad * 8];
            short8 k1 = *(const short8*)&Ks[j * 16 + fr][32 + quad * 8];
            f32x4 acc = {};
            acc = __builtin_amdgcn_mfma_f32_16x16x32_bf16(q0, k0, acc, 0, 0, 0);
            acc = __builtin_amdgcn_mfma_f32_16x16x32_bf16(q1, k1, acc, 0, 0, 0);
#pragma unroll
            for (int r = 0; r < 4; ++r) {
                float p = __expf(acc[r] * 0.125f);
                unsigned hb = bf16_rtne_bits(p);
                lsum += __uint_as_float(hb << 16);
                Ps[wv * 16 + quad * 4 + r][j * 16 + fr] = (short)hb;
            }
        }
        __syncthreads();

        // O += P @ V
        short8 p0 = *(const short8*)&Ps[wv * 16 + fr][quad * 8];
        short8 p1 = *(const short8*)&Ps[wv * 16 + fr][32 + quad * 8];
#pragma unroll
        for (int j = 0; j < 4; ++j) {
            short8 v0 = *(const short8*)&Vt[j * 16 + fr][quad * 8];
            short8 v1 = *(const short8*)&Vt[j * 16 + fr][32 + quad * 8];
            oacc[j] = __builtin_amdgcn_mfma_f32_16x16x32_bf16(p0, v0, oacc[j], 0, 0, 0);
            oacc[j] = __builtin_amdgcn_mfma_f32_16x16x32_bf16(p1, v1, oacc[j], 0, 0, 0);
        }
    }

    // write unnormalized O as bf16 (feeds out-proj GEMM)
#pragma unroll
    for (int j = 0; j < 4; ++j)
#pragma unroll
        for (int r = 0; r < 4; ++r)
            attnb[(size_t)(t0 + wv * 16 + quad * 4 + r) * DIM + h * HDIM + j * 16 + fr] =
                (short)bf16_rtne_bits(oacc[j][r]);

    red[tid] = lsum;
    __syncthreads();
    for (int off = 128; off > 0; off >>= 1) {
        if (tid < off) red[tid] += red[tid + off];
        __syncthreads();
    }
    if (tid == 0) atomicAdd(&g_Lsum[h], red[0]);
}

extern "C" void kernel_launch(void* const* d_in, const int* in_sizes, int n_in,
                              void* d_out, int out_size, void* d_ws, size_t ws_size,
                              hipStream_t stream)
{
    const float* x     = (const float*)d_in[0];   // [4096, 1024]
    const float* W_in  = (const float*)d_in[1];   // [3072, 1024]
    const float* W_out = (const float*)d_in[2];   // [1024, 1024]
    float* out = (float*)d_out;                   // [4096, 1024] fp32

    char* ws = (char*)d_ws;
    short* xb    = (short*)(ws);                          //  8 MiB @ 0
    short* wib   = (short*)(ws + (8u << 20));             //  6 MiB @ 8M
    short* wob   = (short*)(ws + (14u << 20));            //  2 MiB @ 14M
    short* qkvb  = (short*)(ws + (16u << 20));            // 24 MiB @ 16M
    short* attnb = (short*)(ws + (40u << 20));            //  8 MiB @ 40M
    // total 48 MiB (< previously proven 64 MiB)

    zeroL<<<1, 64, 0, stream>>>();

    conv_bf16<<<(TLEN * DIM / 4 + 255) / 256, 256, 0, stream>>>(x, xb, TLEN * DIM / 4);
    conv_bf16<<<(QKV_COLS * DIM / 4 + 255) / 256, 256, 0, stream>>>(W_in, wib, QKV_COLS * DIM / 4);

    // qkv = x @ W_in^T  (bf16 MFMA)
    gemm_bt<true><<<dim3(TLEN / 128, QKV_COLS / 128), 256, 0, stream>>>(
        xb, wib, qkvb, TLEN, QKV_COLS, DIM);

    attn_mfma<<<dim3(TLEN / 64, NHEAD), 256, 0, stream>>>(qkvb, attnb);

    recipL<<<1, 64, 0, stream>>>();
    conv_wout<<<(DIM * DIM / 4 + 255) / 256, 256, 0, stream>>>(W_out, wob);

    // out = attn' @ (W_out/L)^T  (bf16 MFMA, fp32 out)
    gemm_bt<false><<<dim3(TLEN / 128, DIM / 128), 256, 0, stream>>>(
        attnb, wob, out, TLEN, DIM, DIM);
}

// Round 6
// 299.153 us; speedup vs baseline: 6.6592x; 1.0682x over previous
//
#include <hip/hip_runtime.h>

#define TLEN 4096
#define DIM 1024
#define NHEAD 16
#define HDIM 64
#define QKV_COLS (3 * DIM)
#define QSCALE 0.125f

typedef __attribute__((ext_vector_type(8))) short short8;   // 8 bf16 = 4 VGPR (MFMA A/B frag)
typedef __attribute__((ext_vector_type(4))) float f32x4;    // MFMA C/D frag

struct alignas(8) s4 { short v[4]; };

__device__ float g_Lsum[NHEAD];
__device__ float g_recipL[NHEAD];

__global__ void zeroL() {
    if (threadIdx.x < NHEAD) g_Lsum[threadIdx.x] = 0.0f;
}
__global__ void recipL() {
    if (threadIdx.x < NHEAD) g_recipL[threadIdx.x] = 1.0f / g_Lsum[threadIdx.x];
}

__device__ __forceinline__ unsigned bf16_rtne_bits(float x) {
    unsigned u = __float_as_uint(x);
    return (u + 0x7fffu + ((u >> 16) & 1u)) >> 16;
}

// fp32 -> bf16 (RTNE), vectorized; n4 = element count / 4.
__global__ __launch_bounds__(256) void conv_bf16(
    const float* __restrict__ src, short* __restrict__ dst, int n4)
{
    int i = blockIdx.x * 256 + threadIdx.x;
    if (i < n4) {
        float4 v = ((const float4*)src)[i];
        s4 o;
        o.v[0] = (short)bf16_rtne_bits(v.x);
        o.v[1] = (short)bf16_rtne_bits(v.y);
        o.v[2] = (short)bf16_rtne_bits(v.z);
        o.v[3] = (short)bf16_rtne_bits(v.w);
        ((s4*)dst)[i] = o;
    }
}

// W_out [1024,1024] -> bf16 with per-head 1/L folded in (k-group = k/64).
__global__ __launch_bounds__(256) void conv_wout(
    const float* __restrict__ src, short* __restrict__ dst)
{
    int i = blockIdx.x * 256 + threadIdx.x;   // over 1024*1024/4
    float s = g_recipL[(i & 255) >> 4];       // k = (i&255)*4; head = k>>6
    float4 v = ((const float4*)src)[i];
    s4 o;
    o.v[0] = (short)bf16_rtne_bits(v.x * s);
    o.v[1] = (short)bf16_rtne_bits(v.y * s);
    o.v[2] = (short)bf16_rtne_bits(v.z * s);
    o.v[3] = (short)bf16_rtne_bits(v.w * s);
    ((s4*)dst)[i] = o;
}

// C = A @ B^T, bf16 MFMA. 128x128 tile, 4 waves 2x2, BK=32.
// SCALE_Q: multiply output cols n < DIM by QSCALE (pre-scales Q for attention).
template <bool OUT_BF16, bool SCALE_Q>
__global__ __launch_bounds__(256) void gemm_bt(
    const short* __restrict__ A, const short* __restrict__ B,
    void* __restrict__ Cout, int M, int N, int K)
{
    __shared__ short As[128][32];
    __shared__ short Bs[128][32];
    const int tid  = threadIdx.x;
    const int wv   = tid >> 6, lane = tid & 63;
    const int fr   = lane & 15, quad = lane >> 4;
    const int wm   = (wv >> 1) * 64, wn = (wv & 1) * 64;
    const int m0 = blockIdx.x * 128, n0 = blockIdx.y * 128;

    f32x4 acc[4][4] = {};

    for (int k0 = 0; k0 < K; k0 += 32) {
        __syncthreads();
#pragma unroll
        for (int c = tid; c < 512; c += 256) {
            int row = c >> 2, col = (c & 3) * 8;
            *(uint4*)&As[row][col] = *(const uint4*)(A + (size_t)(m0 + row) * K + k0 + col);
            *(uint4*)&Bs[row][col] = *(const uint4*)(B + (size_t)(n0 + row) * K + k0 + col);
        }
        __syncthreads();

        short8 af[4], bfr[4];
#pragma unroll
        for (int i = 0; i < 4; ++i) {
            af[i]  = *(const short8*)&As[wm + i * 16 + fr][quad * 8];
            bfr[i] = *(const short8*)&Bs[wn + i * 16 + fr][quad * 8];
        }
#pragma unroll
        for (int i = 0; i < 4; ++i)
#pragma unroll
            for (int j = 0; j < 4; ++j)
                acc[i][j] = __builtin_amdgcn_mfma_f32_16x16x32_bf16(af[i], bfr[j], acc[i][j], 0, 0, 0);
    }

    const float sc = (SCALE_Q && n0 < DIM) ? QSCALE : 1.0f;
#pragma unroll
    for (int i = 0; i < 4; ++i)
#pragma unroll
        for (int j = 0; j < 4; ++j)
#pragma unroll
            for (int r = 0; r < 4; ++r) {
                size_t off = (size_t)(m0 + wm + i * 16 + quad * 4 + r) * N + n0 + wn + j * 16 + fr;
                float v = acc[i][j][r] * sc;
                if (OUT_BF16)
                    ((short*)Cout)[off] = (short)bf16_rtne_bits(v);
                else
                    ((float*)Cout)[off] = v;
            }
}

// One block per (128-row Q tile, head); 4 waves, each owns a 32-row t-strip.
// S^T = mfma(K,Q) so P lands s-consecutive per lane -> b64 LDS stores.
// PV as O^T = mfma(V^T, P) -> b64 global stores. Q pre-scaled by 0.125.
// P truncated to bf16; lsum sums the truncated values (bias cancels in 1/L).
__global__ __launch_bounds__(256) void attn_mfma(
    const short* __restrict__ qkvb, short* __restrict__ attnb)
{
    __shared__ short Ks[64][72];    // [s][d]
    __shared__ short Vt[64][72];    // [d][s]
    __shared__ short Ps[128][72];   // Q staged here first ([t][d]), then P [t][s]
    __shared__ float red[256];

    const int tid = threadIdx.x;
    const int t0 = blockIdx.x * 128;
    const int h  = blockIdx.y;
    const int lr  = tid >> 2;          // 0..63
    const int lc4 = (tid & 3) << 2;    // 0,4,8,12
    const int wv   = tid >> 6;
    const int lane = tid & 63;
    const int fr   = lane & 15;
    const int quad = lane >> 4;
    const int tb   = wv * 32;          // wave's t-strip base within the tile

    // ---- stage Q (128x64, already x0.125) into the Ps region ----
#pragma unroll
    for (int half = 0; half < 128; half += 64)
#pragma unroll
        for (int c0 = 0; c0 < HDIM; c0 += 16) {
            int d = c0 + lc4;
            *(s4*)&Ps[half + lr][d] =
                *(const s4*)(qkvb + (size_t)(t0 + half + lr) * QKV_COLS + h * HDIM + d);
        }
    __syncthreads();

    // Q fragments (B-operand): [t = tb+jt*16+fr][d = kh*32+quad*8 ..]
    short8 qf[2][2];
#pragma unroll
    for (int jt = 0; jt < 2; ++jt)
#pragma unroll
        for (int kh = 0; kh < 2; ++kh)
            qf[jt][kh] = *(const short8*)&Ps[tb + jt * 16 + fr][kh * 32 + quad * 8];

    f32x4 oaccT[4][2] = {};   // [jd][jt], O^T[d][t]
    float lsum = 0.0f;

    for (int s0 = 0; s0 < TLEN; s0 += 64) {
        __syncthreads();   // prev-iter readers of Ks/Vt/Ps done
#pragma unroll
        for (int c0 = 0; c0 < HDIM; c0 += 16) {
            int d = c0 + lc4;
            *(s4*)&Ks[lr][d] =
                *(const s4*)(qkvb + (size_t)(s0 + lr) * QKV_COLS + DIM + h * HDIM + d);
            s4 vv = *(const s4*)(qkvb + (size_t)(s0 + lr) * QKV_COLS + 2 * DIM + h * HDIM + d);
            Vt[d + 0][lr] = vv.v[0];
            Vt[d + 1][lr] = vv.v[1];
            Vt[d + 2][lr] = vv.v[2];
            Vt[d + 3][lr] = vv.v[3];
        }
        __syncthreads();

        // ---- S^T = K.Q^T: mfma(K-frag, Q-frag) -> (s = i*16+quad*4+r, t = tb+jt*16+fr)
#pragma unroll
        for (int i = 0; i < 4; ++i) {
            short8 ka0 = *(const short8*)&Ks[i * 16 + fr][quad * 8];
            short8 ka1 = *(const short8*)&Ks[i * 16 + fr][32 + quad * 8];
#pragma unroll
            for (int jt = 0; jt < 2; ++jt) {
                f32x4 acc = {};
                acc = __builtin_amdgcn_mfma_f32_16x16x32_bf16(ka0, qf[jt][0], acc, 0, 0, 0);
                acc = __builtin_amdgcn_mfma_f32_16x16x32_bf16(ka1, qf[jt][1], acc, 0, 0, 0);
                unsigned u0 = __float_as_uint(__expf(acc[0]));
                unsigned u1 = __float_as_uint(__expf(acc[1]));
                unsigned u2 = __float_as_uint(__expf(acc[2]));
                unsigned u3 = __float_as_uint(__expf(acc[3]));
                lsum += __uint_as_float(u0 & 0xffff0000u);
                lsum += __uint_as_float(u1 & 0xffff0000u);
                lsum += __uint_as_float(u2 & 0xffff0000u);
                lsum += __uint_as_float(u3 & 0xffff0000u);
                uint2 pk;
                pk.x = (u0 >> 16) | (u1 & 0xffff0000u);
                pk.y = (u2 >> 16) | (u3 & 0xffff0000u);
                *(uint2*)&Ps[tb + jt * 16 + fr][i * 16 + quad * 4] = pk;
            }
        }
        // No barrier: each wave reads back only its own P rows; Vt staged pre-barrier.

        // ---- O^T += V^T.P: mfma(Vt-frag, P-frag) -> (d = jd*16+quad*4+r, t = tb+jt*16+fr)
        short8 pb[2][2];
#pragma unroll
        for (int jt = 0; jt < 2; ++jt)
#pragma unroll
            for (int kh = 0; kh < 2; ++kh)
                pb[jt][kh] = *(const short8*)&Ps[tb + jt * 16 + fr][kh * 32 + quad * 8];
#pragma unroll
        for (int jd = 0; jd < 4; ++jd) {
            short8 va0 = *(const short8*)&Vt[jd * 16 + fr][quad * 8];
            short8 va1 = *(const short8*)&Vt[jd * 16 + fr][32 + quad * 8];
#pragma unroll
            for (int jt = 0; jt < 2; ++jt) {
                oaccT[jd][jt] = __builtin_amdgcn_mfma_f32_16x16x32_bf16(va0, pb[jt][0], oaccT[jd][jt], 0, 0, 0);
                oaccT[jd][jt] = __builtin_amdgcn_mfma_f32_16x16x32_bf16(va1, pb[jt][1], oaccT[jd][jt], 0, 0, 0);
            }
        }
    }

    // ---- epilogue: O^T[d][t] -> attnb[t][h*64+d], bf16, b64 stores ----
#pragma unroll
    for (int jt = 0; jt < 2; ++jt)
#pragma unroll
        for (int jd = 0; jd < 4; ++jd) {
            unsigned u0 = bf16_rtne_bits(oaccT[jd][jt][0]);
            unsigned u1 = bf16_rtne_bits(oaccT[jd][jt][1]);
            unsigned u2 = bf16_rtne_bits(oaccT[jd][jt][2]);
            unsigned u3 = bf16_rtne_bits(oaccT[jd][jt][3]);
            uint2 pk;
            pk.x = u0 | (u1 << 16);
            pk.y = u2 | (u3 << 16);
            *(uint2*)(attnb + (size_t)(t0 + tb + jt * 16 + fr) * DIM + h * HDIM + jd * 16 + quad * 4) = pk;
        }

    // ---- block-reduce lsum, one atomic per block ----
    red[tid] = lsum;
    __syncthreads();
    for (int off = 128; off > 0; off >>= 1) {
        if (tid < off) red[tid] += red[tid + off];
        __syncthreads();
    }
    if (tid == 0) atomicAdd(&g_Lsum[h], red[0]);
}

extern "C" void kernel_launch(void* const* d_in, const int* in_sizes, int n_in,
                              void* d_out, int out_size, void* d_ws, size_t ws_size,
                              hipStream_t stream)
{
    const float* x     = (const float*)d_in[0];   // [4096, 1024]
    const float* W_in  = (const float*)d_in[1];   // [3072, 1024]
    const float* W_out = (const float*)d_in[2];   // [1024, 1024]
    float* out = (float*)d_out;                   // [4096, 1024] fp32

    char* ws = (char*)d_ws;
    short* xb    = (short*)(ws);                          //  8 MiB @ 0
    short* wib   = (short*)(ws + (8u << 20));             //  6 MiB @ 8M
    short* wob   = (short*)(ws + (14u << 20));            //  2 MiB @ 14M
    short* qkvb  = (short*)(ws + (16u << 20));            // 24 MiB @ 16M
    short* attnb = (short*)(ws + (40u << 20));            //  8 MiB @ 40M

    zeroL<<<1, 64, 0, stream>>>();

    conv_bf16<<<(TLEN * DIM / 4 + 255) / 256, 256, 0, stream>>>(x, xb, TLEN * DIM / 4);
    conv_bf16<<<(QKV_COLS * DIM / 4 + 255) / 256, 256, 0, stream>>>(W_in, wib, QKV_COLS * DIM / 4);

    // qkv = x @ W_in^T  (bf16 MFMA; Q columns pre-scaled by 0.125)
    gemm_bt<true, true><<<dim3(TLEN / 128, QKV_COLS / 128), 256, 0, stream>>>(
        xb, wib, qkvb, TLEN, QKV_COLS, DIM);

    attn_mfma<<<dim3(TLEN / 128, NHEAD), 256, 0, stream>>>(qkvb, attnb);

    recipL<<<1, 64, 0, stream>>>();
    conv_wout<<<(DIM * DIM / 4 + 255) / 256, 256, 0, stream>>>(W_out, wob);

    // out = attn' @ (W_out/L)^T  (bf16 MFMA, fp32 out)
    gemm_bt<false, false><<<dim3(TLEN / 128, DIM / 128), 256, 0, stream>>>(
        attnb, wob, out, TLEN, DIM, DIM);
}